// Round 11
// baseline (898.973 us; speedup 1.0000x reference)
//
#include <hip/hip_runtime.h>

typedef __bf16 bf16x8 __attribute__((ext_vector_type(8)));
typedef float  f32x4  __attribute__((ext_vector_type(4)));
typedef unsigned short us8 __attribute__((ext_vector_type(8)));

__device__ __forceinline__ unsigned short f2bf(float f) {
    union { float f; unsigned u; } c; c.f = f;
    unsigned u = c.u;
    u += 0x7FFFu + ((u >> 16) & 1u);   // RNE; inputs finite
    return (unsigned short)(u >> 16);
}
__device__ __forceinline__ float sigf(float v) { return 1.0f / (1.0f + __expf(-v)); }

// -------- wxform: OIHW f32 -> [tap][co][ci] bf16 (16 KB/tap, L2-resident) ----
__global__ void __launch_bounds__(256) wxform(const float* __restrict__ W,
                                              unsigned short* __restrict__ wpad) {
    int o = blockIdx.x * 256 + threadIdx.x;        // 9*128*64 = 73728
    if (o < 9 * 8192) {
        int tap = o >> 13;
        int r   = o & 8191;
        int co  = r >> 6, ci = r & 63;
        wpad[o] = f2bf(W[co * 576 + ci * 9 + tap]);   // W[co][ci][kh][kw]
    }
}

// x-ring: 10 rows x 18 px x 64 ci bf16. Pixel at local col c (0..17) of ring
// slot so lives at byte (so*18+c)*128; granule g (8 ci) at slot g ^ ((c>>1)&7).
struct SmemT { unsigned short x[10 * 18 * 64]; };   // 23040 B -> 3 blocks/CU

// ============ conv_ring2: v8 structure, straight-line taps (no scratch) ======
// Block 256 thr = 4 waves (wave = 32-co slice). Tile = 4 rows x 16 cols x 128co;
// strip of 8 tiles (32 rows). Weights: NAMED reg-double-buffered B-frags from
// L2-resident wpad (cA*/cB*, explicit alternation -> nothing runtime-indexed).
// x staged in-kernel: chunk A issued at tile start, written after tap 2; chunk
// B (reusing fA regs) issued after tap 2, written after tap 5. ONE barrier/tile.
__global__ void __launch_bounds__(256, 3)
conv_ring(const float* __restrict__ x,
          const unsigned short* __restrict__ wpad,
          const float* __restrict__ bias,
          float* __restrict__ out)
{
    __shared__ __align__(16) SmemT sm;
    __shared__ float red[4];

    const int tid  = threadIdx.x;
    const int coq  = tid >> 6;        // wave id = co quad (32 co)
    const int lane = tid & 63;
    const int lq   = lane >> 4;
    const int lm   = lane & 15;

    // XCD-aware decode (1-D grid, consecutive IDs round-robin XCDs): all 32
    // blocks of one image land on one XCD -> x line-sharing + wpad L2-resident.
    const int bid = blockIdx.x;                   // 0..2047
    const int xcd = bid & 7, j = bid >> 3;
    const int n   = xcd + 8 * (j >> 5);           // 0..63
    const int r5  = j & 31;
    const int rtg = r5 >> 3;                      // 0..3  row strip (32 tall)
    const int ct  = r5 & 7;                       // 0..7  col tile (16 wide)

    const int h0s = rtg * 32;
    const int w0  = ct * 16;
    const float* xn = x + (size_t)n * 1048576;

    // ---- prologue: stage rows h0s..h0s+5 (432 tasks = 8g * 6r * 9wq) ----
    #pragma unroll
    for (int it = 0; it < 2; ++it) {
        int t = it * 256 + tid;
        if (t < 432) {
            int g = t / 54, rem = t % 54;
            int r = rem / 9, wq = rem % 9;
            int h = h0s + r, w = w0 + 2 * wq;     // h <= 101, always valid
            bool ok = (w < 128);
            const float* src = xn + (size_t)(g * 8) * 16384 + h * 128 + w;
            us8 ua, ub;
            #pragma unroll
            for (int jj = 0; jj < 8; ++jj) {
                float2 v = ok ? *(const float2*)(src + jj * 16384) : make_float2(0.f, 0.f);
                ua[jj] = f2bf(v.x); ub[jj] = f2bf(v.y);
            }
            int so = h % 10;
            char* base = (char*)sm.x + (so * 18 + 2 * wq) * 128 + ((g ^ (wq & 7)) << 4);
            *(us8*)(base)       = ua;
            *(us8*)(base + 128) = ub;
        }
    }

    // ---- per-lane weight base: co = coq*32 + ntl*16 + lm; f = ntl*2+kc ----
    const char* wb = (const char*)wpad + ((coq * 32 + lm) << 7) + (lq << 4);
#define LDBF(dst, tapn, f) \
    dst = *(const bf16x8*)(wb + (tapn) * 16384 + ((f) >> 1) * 2048 + ((f) & 1) * 64);

    bf16x8 cA0, cA1, cA2, cA3, cB0, cB1, cB2, cB3;
    LDBF(cA0, 0, 0) LDBF(cA1, 0, 1) LDBF(cA2, 0, 2) LDBF(cA3, 0, 3)

    float bv[2] = { bias[coq * 32 + lm], bias[coq * 32 + 16 + lm] };

    // A-frag byte offsets within a ring row (local col c = lm+kw)
    int sl[3][2];
    #pragma unroll
    for (int kw = 0; kw < 3; ++kw)
        #pragma unroll
        for (int kc = 0; kc < 2; ++kc)
            sl[kw][kc] = (lm + kw) * 128 +
                ((((kc << 2) | lq) ^ (((lm + kw) >> 1) & 7)) << 4);

    f32x4 acc[4][2];
    #pragma unroll
    for (int rr = 0; rr < 4; ++rr) {
        acc[rr][0] = (f32x4){0.f, 0.f, 0.f, 0.f};
        acc[rr][1] = (f32x4){0.f, 0.f, 0.f, 0.f};
    }
    float part = 0.0f;

    // staging task coords: task t in [0,288): g=t/36, r=(t%36)/9, wq=t%9
    const int sAg = tid / 36, sAr = (tid % 36) / 9, sAwq = tid % 9;   // 0..255
    const int tB  = 256 + tid;
    const int sBg = tB / 36, sBr = (tB % 36) / 9, sBwq = tB % 9;      // 256..287

    __syncthreads();   // prologue x visible

    const char* smb = (const char*)sm.x;

// one tap = 4 named next-tap B loads + 8 ds_read_b128 + 16 MFMA, all static
#define TAPM(kh, kw, C0, C1, C2, C3, N0, N1, N2, N3, NTAP)                         \
    {                                                                              \
        LDBF(N0, NTAP, 0) LDBF(N1, NTAP, 1) LDBF(N2, NTAP, 2) LDBF(N3, NTAP, 3)    \
        bf16x8 a0, a1, a2, a3;                                                     \
        a0 = *(const bf16x8*)(smb + rb[(kh) + 0] + sl[(kw)][0]);                   \
        a1 = *(const bf16x8*)(smb + rb[(kh) + 1] + sl[(kw)][0]);                   \
        a2 = *(const bf16x8*)(smb + rb[(kh) + 2] + sl[(kw)][0]);                   \
        a3 = *(const bf16x8*)(smb + rb[(kh) + 3] + sl[(kw)][0]);                   \
        acc[0][0] = __builtin_amdgcn_mfma_f32_16x16x32_bf16(a0, C0, acc[0][0], 0, 0, 0); \
        acc[1][0] = __builtin_amdgcn_mfma_f32_16x16x32_bf16(a1, C0, acc[1][0], 0, 0, 0); \
        acc[2][0] = __builtin_amdgcn_mfma_f32_16x16x32_bf16(a2, C0, acc[2][0], 0, 0, 0); \
        acc[3][0] = __builtin_amdgcn_mfma_f32_16x16x32_bf16(a3, C0, acc[3][0], 0, 0, 0); \
        acc[0][1] = __builtin_amdgcn_mfma_f32_16x16x32_bf16(a0, C2, acc[0][1], 0, 0, 0); \
        acc[1][1] = __builtin_amdgcn_mfma_f32_16x16x32_bf16(a1, C2, acc[1][1], 0, 0, 0); \
        acc[2][1] = __builtin_amdgcn_mfma_f32_16x16x32_bf16(a2, C2, acc[2][1], 0, 0, 0); \
        acc[3][1] = __builtin_amdgcn_mfma_f32_16x16x32_bf16(a3, C2, acc[3][1], 0, 0, 0); \
        a0 = *(const bf16x8*)(smb + rb[(kh) + 0] + sl[(kw)][1]);                   \
        a1 = *(const bf16x8*)(smb + rb[(kh) + 1] + sl[(kw)][1]);                   \
        a2 = *(const bf16x8*)(smb + rb[(kh) + 2] + sl[(kw)][1]);                   \
        a3 = *(const bf16x8*)(smb + rb[(kh) + 3] + sl[(kw)][1]);                   \
        acc[0][0] = __builtin_amdgcn_mfma_f32_16x16x32_bf16(a0, C1, acc[0][0], 0, 0, 0); \
        acc[1][0] = __builtin_amdgcn_mfma_f32_16x16x32_bf16(a1, C1, acc[1][0], 0, 0, 0); \
        acc[2][0] = __builtin_amdgcn_mfma_f32_16x16x32_bf16(a2, C1, acc[2][0], 0, 0, 0); \
        acc[3][0] = __builtin_amdgcn_mfma_f32_16x16x32_bf16(a3, C1, acc[3][0], 0, 0, 0); \
        acc[0][1] = __builtin_amdgcn_mfma_f32_16x16x32_bf16(a0, C3, acc[0][1], 0, 0, 0); \
        acc[1][1] = __builtin_amdgcn_mfma_f32_16x16x32_bf16(a1, C3, acc[1][1], 0, 0, 0); \
        acc[2][1] = __builtin_amdgcn_mfma_f32_16x16x32_bf16(a2, C3, acc[2][1], 0, 0, 0); \
        acc[3][1] = __builtin_amdgcn_mfma_f32_16x16x32_bf16(a3, C3, acc[3][1], 0, 0, 0); \
    }

    int sb = h0s % 10;                 // ring slot of tile row 0
    for (int s = 0; s < 8; ++s) {
        const bool more = (s < 7);
        int rb[6];                     // ring row byte-bases sb..sb+5 (static idx)
        #pragma unroll
        for (int i = 0; i < 6; ++i) { int so = sb + i; if (so >= 10) so -= 10; rb[i] = so * 2304; }

        // ---- issue chunk A (256 tasks, all threads) ----
        float2 fA[8];
        if (more) {
            int h = h0s + s * 4 + 6 + sAr, w = w0 + 2 * sAwq;
            bool okA = (h < 128) && (w < 128);
            const float* src = xn + (size_t)(sAg * 8) * 16384 + h * 128 + w;
            #pragma unroll
            for (int jj = 0; jj < 8; ++jj)
                fA[jj] = okA ? *(const float2*)(src + jj * 16384) : make_float2(0.f, 0.f);
        }

        TAPM(0, 0, cA0, cA1, cA2, cA3, cB0, cB1, cB2, cB3, 1)
        TAPM(0, 1, cB0, cB1, cB2, cB3, cA0, cA1, cA2, cA3, 2)
        TAPM(0, 2, cA0, cA1, cA2, cA3, cB0, cB1, cB2, cB3, 3)

        // ---- finish chunk A; issue chunk B into the same regs ----
        if (more) {
            us8 ua, ub;
            #pragma unroll
            for (int jj = 0; jj < 8; ++jj) { ua[jj] = f2bf(fA[jj].x); ub[jj] = f2bf(fA[jj].y); }
            int so = sb + 6 + sAr; if (so >= 10) so -= 10;
            char* base = (char*)sm.x + (so * 18 + 2 * sAwq) * 128 + ((sAg ^ (sAwq & 7)) << 4);
            *(us8*)(base)       = ua;
            *(us8*)(base + 128) = ub;
            if (tid < 32) {            // 32 remaining tasks
                int h = h0s + s * 4 + 6 + sBr, w = w0 + 2 * sBwq;
                bool okB = (h < 128) && (w < 128);
                const float* src = xn + (size_t)(sBg * 8) * 16384 + h * 128 + w;
                #pragma unroll
                for (int jj = 0; jj < 8; ++jj)
                    fA[jj] = okB ? *(const float2*)(src + jj * 16384) : make_float2(0.f, 0.f);
            }
        }

        TAPM(1, 0, cB0, cB1, cB2, cB3, cA0, cA1, cA2, cA3, 4)
        TAPM(1, 1, cA0, cA1, cA2, cA3, cB0, cB1, cB2, cB3, 5)
        TAPM(1, 2, cB0, cB1, cB2, cB3, cA0, cA1, cA2, cA3, 6)

        // ---- finish chunk B ----
        if (more && tid < 32) {
            us8 ua, ub;
            #pragma unroll
            for (int jj = 0; jj < 8; ++jj) { ua[jj] = f2bf(fA[jj].x); ub[jj] = f2bf(fA[jj].y); }
            int so = sb + 6 + sBr; if (so >= 10) so -= 10;
            char* base = (char*)sm.x + (so * 18 + 2 * sBwq) * 128 + ((sBg ^ (sBwq & 7)) << 4);
            *(us8*)(base)       = ua;
            *(us8*)(base + 128) = ub;
        }

        TAPM(2, 0, cA0, cA1, cA2, cA3, cB0, cB1, cB2, cB3, 7)
        TAPM(2, 1, cB0, cB1, cB2, cB3, cA0, cA1, cA2, cA3, 8)
        TAPM(2, 2, cA0, cA1, cA2, cA3, cB0, cB1, cB2, cB3, 0)   // prefetch tap0
        cA0 = cB0; cA1 = cB1; cA2 = cB2; cA3 = cB3;             // restore parity

        // ---- per-tile epilogue: pool + bias + sigmoid ----
        #pragma unroll
        for (int p = 0; p < 2; ++p) {
            int ph = rtg * 16 + s * 2 + p;              // pool row
            if (ph < 63) {
                int pwb = ct * 8 + lq * 2;
                #pragma unroll
                for (int ntl = 0; ntl < 2; ++ntl) {
                    f32x4 sv = acc[2 * p][ntl] + acc[2 * p + 1][ntl];  // vert pool
                    float p0 = sv[0] + sv[1];                          // cols (0,1)
                    float p1 = sv[2] + sv[3];                          // cols (2,3)
                    float bbv = bv[ntl];
                    if (pwb < 63)     part += sigf(0.25f * p0 + bbv);
                    if (pwb + 1 < 63) part += sigf(0.25f * p1 + bbv);
                }
            }
        }
        #pragma unroll
        for (int rr = 0; rr < 4; ++rr) {
            acc[rr][0] = (f32x4){0.f, 0.f, 0.f, 0.f};
            acc[rr][1] = (f32x4){0.f, 0.f, 0.f, 0.f};
        }

        sb += 4; if (sb >= 10) sb -= 10;
        __syncthreads();   // staged rows visible; read-done slots reusable
    }

    // ---- block reduce -> one atomicAdd per block ----
    #pragma unroll
    for (int off = 32; off > 0; off >>= 1)
        part += __shfl_down(part, off, 64);
    if (lane == 0) red[coq] = part;
    __syncthreads();
    if (tid == 0) atomicAdd(&out[n], red[0] + red[1] + red[2] + red[3]);
}

extern "C" void kernel_launch(void* const* d_in, const int* in_sizes, int n_in,
                              void* d_out, int out_size, void* d_ws, size_t ws_size,
                              hipStream_t stream) {
    const float* x = (const float*)d_in[0];
    const float* W = (const float*)d_in[1];
    const float* b = (const float*)d_in[2];
    float* out = (float*)d_out;
    unsigned short* wpad = (unsigned short*)d_ws;   // 147,456 B used

    hipMemsetAsync(d_out, 0, 64 * sizeof(float), stream);
    wxform<<<288, 256, 0, stream>>>(W, wpad);
    conv_ring<<<2048, 256, 0, stream>>>(x, wpad, b, out);
}